// Round 10
// baseline (1097.065 us; speedup 1.0000x reference)
//
#include <hip/hip_runtime.h>
#include <hip/hip_bf16.h>
#include <math.h>

typedef __bf16 bf16;
typedef __bf16 bf16x8 __attribute__((ext_vector_type(8)));
typedef __bf16 bf16x4 __attribute__((ext_vector_type(4)));
typedef short  s16x4  __attribute__((ext_vector_type(4)));
typedef float  f32x4  __attribute__((ext_vector_type(4)));

#define MFMA32(a,b,c) __builtin_amdgcn_mfma_f32_16x16x32_bf16((a),(b),(c),0,0,0)
#define MFMA16(a,b,c) __builtin_amdgcn_mfma_f32_16x16x16bf16_1k((a),(b),(c),0,0,0)
#define EXP2F(x) __builtin_amdgcn_exp2f(x)
// async global->LDS, 16B per lane; LDS dest is wave-uniform base + lane*16 (m104/m108)
#define GLL16(gp, lp) __builtin_amdgcn_global_load_lds(\
    (const __attribute__((address_space(1))) void*)(gp), \
    (__attribute__((address_space(3))) void*)(lp), 16, 0, 0)

__device__ __forceinline__ float wave_sum(float v){
#pragma unroll
  for(int off=1; off<64; off<<=1) v += __shfl_xor(v, off);
  return v;
}

// ---------------- fused (add) + layernorm -> bf16 (round-1 verbatim) ----------------
__global__ __launch_bounds__(256) void add_ln_kernel(
    const float* __restrict__ xsrc, const float* __restrict__ addsrc,
    const float* __restrict__ emb,
    const float* __restrict__ gw, const float* __restrict__ gb,
    float* __restrict__ xout, bf16* __restrict__ hout)
{
  const int row = blockIdx.x;
  const int t = threadIdx.x;
  const size_t rbase = (size_t)row * 1024;
  float4 x = ((const float4*)(xsrc + rbase))[t];
  if(addsrc){
    float4 a = ((const float4*)(addsrc + rbase))[t];
    x.x += a.x; x.y += a.y; x.z += a.z; x.w += a.w;
  }
  if(emb){
    float4 e = ((const float4*)emb)[t];
    x.x += e.x; x.y += e.y; x.z += e.z; x.w += e.w;
  }
  if(xout) ((float4*)(xout + rbase))[t] = x;

  float s = x.x + x.y + x.z + x.w;
  float q = x.x*x.x + x.y*x.y + x.z*x.z + x.w*x.w;
  s = wave_sum(s); q = wave_sum(q);
  __shared__ float red[8];
  const int w = t >> 6;
  if((t & 63) == 0){ red[w] = s; red[4+w] = q; }
  __syncthreads();
  s = red[0]+red[1]+red[2]+red[3];
  q = red[4]+red[5]+red[6]+red[7];
  const float mean = s * (1.0f/1024.0f);
  const float var  = q * (1.0f/1024.0f) - mean*mean;
  const float inv  = rsqrtf(var + 1e-5f);

  float4 wv = ((const float4*)gw)[t];
  float4 bv = ((const float4*)gb)[t];
  bf16x4 hv;
  hv[0] = (bf16)((x.x - mean)*inv*wv.x + bv.x);
  hv[1] = (bf16)((x.y - mean)*inv*wv.y + bv.y);
  hv[2] = (bf16)((x.z - mean)*inv*wv.z + bv.z);
  hv[3] = (bf16)((x.w - mean)*inv*wv.w + bv.w);
  *(bf16x4*)(hout + rbase + t*4) = hv;
}

// ---------------- merged weight packing, LDS-tiled transposes (round-9 verbatim) ----------------
__global__ __launch_bounds__(256) void pack_all_kernel(
    const float* __restrict__ Wq, const float* __restrict__ Wk, const float* __restrict__ Wv,
    const float* __restrict__ fcw, const float* __restrict__ w2,
    const float* __restrict__ w3,  const float* __restrict__ w1,
    bf16* __restrict__ wqkvT, bf16* __restrict__ fcT,
    bf16* __restrict__ w2T,   bf16* __restrict__ w3T, bf16* __restrict__ w1pl)
{
  const int bid = blockIdx.x;
  const int tid = threadIdx.x;
  if(bid >= 1792){                       // w1 cast: 2M elems, flat coalesced
    const int i0 = (bid-1792)*2048 + tid*8;
    float4 a = *(const float4*)(w1 + i0);
    float4 b = *(const float4*)(w1 + i0 + 4);
    bf16x8 o;
    o[0]=(bf16)a.x; o[1]=(bf16)a.y; o[2]=(bf16)a.z; o[3]=(bf16)a.w;
    o[4]=(bf16)b.x; o[5]=(bf16)b.y; o[6]=(bf16)b.z; o[7]=(bf16)b.w;
    *(bf16x8*)(w1pl + i0) = o;
    return;
  }

  __shared__ float tile[64][65];
  const float* src; bf16* dst;
  int src_ld, dst_ld;
  if(bid < 768){                         // qkv
    const int seg = bid >> 8, r8 = bid & 255;
    const int h = r8 >> 4, d0 = (r8 & 15)*64;
    const float* W = (seg==0) ? Wq : (seg==1 ? Wk : Wv);
    src = W + h*65536 + (size_t)d0*64;  src_ld = 64;
    dst = wqkvT + ((size_t)(seg*1024 + h*64))*1024 + d0;  dst_ld = 1024;
  } else if(bid < 1024){                 // fcT
    const int t2 = bid - 768;
    const int k0 = (t2 >> 4)*64, n0 = (t2 & 15)*64;
    src = fcw + (size_t)k0*1024 + n0;  src_ld = 1024;
    dst = fcT + (size_t)n0*1024 + k0;  dst_ld = 1024;
  } else if(bid < 1536){                 // w2T
    const int t2 = bid - 1024;
    const int k0 = (t2 >> 4)*64, n0 = (t2 & 15)*64;
    src = w2 + (size_t)k0*1024 + n0;  src_ld = 1024;
    dst = w2T + (size_t)n0*2048 + k0;  dst_ld = 2048;
  } else {                               // w3T
    const int t2 = bid - 1536;
    const int k0 = (t2 >> 4)*64, n0 = (t2 & 15)*64;
    src = w3 + (size_t)k0*1024 + n0;  src_ld = 1024;
    dst = w3T + (size_t)n0*1024 + k0;  dst_ld = 1024;
  }

  {
    const int r = tid >> 4, c4 = (tid & 15)*4;
#pragma unroll
    for(int p=0; p<4; p++){
      float4 v = *(const float4*)(src + (size_t)(r + 16*p)*src_ld + c4);
      tile[r+16*p][c4]   = v.x;
      tile[r+16*p][c4+1] = v.y;
      tile[r+16*p][c4+2] = v.z;
      tile[r+16*p][c4+3] = v.w;
    }
  }
  __syncthreads();
  {
    const int n = tid >> 2, k16 = (tid & 3)*16;
#pragma unroll
    for(int half=0; half<2; half++){
      bf16x8 o;
#pragma unroll
      for(int j=0; j<8; j++) o[j] = (bf16)tile[k16 + half*8 + j][n];
      *(bf16x8*)(dst + (size_t)n*dst_ld + k16 + half*8) = o;
    }
  }
}

__global__ __launch_bounds__(256) void biasmv_kernel(const float* __restrict__ bin, const bf16* __restrict__ WT,
                                                     const float* __restrict__ badd, float* __restrict__ out, int Kd){
  const int n = blockIdx.x, t = threadIdx.x;
  float acc = 0.f;
  for(int k=t; k<Kd; k+=256) acc += bin[k]*(float)WT[(size_t)n*Kd + k];
  acc = wave_sum(acc);
  __shared__ float red[4];
  if((t&63)==0) red[t>>6] = acc;
  __syncthreads();
  if(t==0) out[n] = red[0]+red[1]+red[2]+red[3] + badd[n];
}

// ---------------- bf16 MFMA GEMM, BK = 64*KH (round-8/9 verbatim) ----------------
template<int EPI, int BLKM, int KH>
__global__ __launch_bounds__(256,2) void gemm_kernel(
    const bf16* __restrict__ A, const bf16* __restrict__ Bt,
    float* __restrict__ outf, bf16* __restrict__ outb,
    bf16* __restrict__ o2, bf16* __restrict__ o3,
    const float* __restrict__ bias, const float* __restrict__ res,
    const float* __restrict__ res2, const float* __restrict__ embn,
    int N, int K)
{
  constexpr int RM = BLKM/32;
  constexpr int HM = BLKM/2;
  constexpr int AISS = BLKM/32;
  __shared__ __align__(16) bf16 As[KH*BLKM*64];
  __shared__ __align__(16) bf16 Bs[KH*128*64];
  const int tid = threadIdx.x, w = tid>>6, lane = tid&63;
  const int quad = lane>>4, l16 = lane&15;
  const int wm = w&1, wn = w>>1;
  const int tn = blockIdx.x, tm = blockIdx.y;

  const int srow = lane>>3;
  const int sch  = (lane&7) ^ srow;
  const bf16* Ag = A  + (size_t)(tm*BLKM + w*8 + srow)*K + sch*8;
  const bf16* Bg = Bt + (size_t)(tn*128  + w*8 + srow)*K + sch*8;

  f32x4 acc[RM][4] = {};

  for(int k0 = 0; k0 < K; k0 += 64*KH){
#pragma unroll
    for(int h=0; h<KH; h++){
#pragma unroll
      for(int i=0;i<AISS;i++) GLL16(Ag + h*64 + (size_t)(i*32)*K, As + h*(BLKM*64) + (w*8 + i*32)*64);
#pragma unroll
      for(int i=0;i<4;i++)    GLL16(Bg + h*64 + (size_t)(i*32)*K, Bs + h*(128*64) + (w*8 + i*32)*64);
    }
    Ag += 64*KH; Bg += 64*KH;
    __syncthreads();
#pragma unroll
    for(int h=0; h<KH; h++){
      const bf16* Ash = As + h*(BLKM*64);
      const bf16* Bsh = Bs + h*(128*64);
      bf16x8 af[RM][2], bfr[4][2];
#pragma unroll
      for(int r=0;r<RM;r++){
        const int row = wm*HM + r*16 + l16;
        const bf16* rp = Ash + row*64;
#pragma unroll
        for(int kc=0;kc<2;kc++)
          af[r][kc] = *(const bf16x8*)(rp + ((kc*4+quad) ^ (row&7))*8);
      }
#pragma unroll
      for(int c=0;c<4;c++){
        const int row = wn*64 + c*16 + l16;
        const bf16* rp = Bsh + row*64;
#pragma unroll
        for(int kc=0;kc<2;kc++)
          bfr[c][kc] = *(const bf16x8*)(rp + ((kc*4+quad) ^ (row&7))*8);
      }
#pragma unroll
      for(int kc=0;kc<2;kc++)
#pragma unroll
        for(int r=0;r<RM;r++)
#pragma unroll
          for(int c=0;c<4;c++)
            acc[r][c] = MFMA32(af[r][kc], bfr[c][kc], acc[r][c]);
    }
    __syncthreads();
  }

  // C/D: col = lane&15, row = quad*4 + reg
#pragma unroll
  for(int r=0;r<RM;r++){
    const int grow0 = tm*BLKM + wm*HM + r*16 + quad*4;
#pragma unroll
    for(int c=0;c<4;c++){
      const int gcol = tn*128 + wn*64 + c*16 + l16;
      float bv = 0.0f;
      if constexpr (EPI>=1 && EPI!=4) bv = bias[gcol];
      if constexpr (EPI==4){
        const int seg = gcol >> 10;          // wave-uniform
        if(seg < 2){
          bf16* op = (seg==0) ? outb : o2;
          const float qs = (seg==0) ? 0.045084439f : 1.0f;
          const int col = gcol & 1023;
#pragma unroll
          for(int g=0; g<4; g++)
            op[(size_t)(grow0+g)*1024 + col] = (bf16)(acc[r][c][g]*qs);
        } else {
          const int col0 = gcol & 1023, hh = col0>>6, kk = col0&63;
          const int btok = grow0>>10, t0 = grow0&1023;
          bf16x4 pv;
#pragma unroll
          for(int g=0; g<4; g++) pv[g] = (bf16)acc[r][c][g];
          *(bf16x4*)(o3 + ((size_t)(btok*16+hh)*64 + kk)*1024 + t0) = pv;
        }
      } else {
        const float ev = (EPI==5) ? embn[gcol] : 0.0f;
#pragma unroll
        for(int g=0; g<4; g++){
          const float vv = acc[r][c][g] + bv;
          const size_t idx = (size_t)(grow0+g)*N + gcol;
          if constexpr (EPI<=1){
            outb[idx] = (bf16)vv;
          } else if constexpr (EPI==2){
            outf[idx] = res[idx] + vv;
          } else if constexpr (EPI==3){
            const float gel = 0.5f*vv*(1.0f + erff(vv*0.70710678118654752f));
            outf[idx] = res[idx] + gel;
          } else {
            const float gel = 0.5f*vv*(1.0f + erff(vv*0.70710678118654752f));
            outf[idx] = res[idx] + gel + res2[idx] + ev;
          }
        }
      }
    }
  }
}

// ---------------- balanced split-K causal attention ----------------
// grid (64 bh, 16 s), 256 threads, round-1 staging/compute structure. Work re-mapped for
// balance (no-max softmax is linear in key partitions -> partials (o,l) add):
//   slot s<8 : q-tile qA=s FULL (s+1 units, diag; O written directly)
//              + HEAD of q-tile qB=15-s (kb in [0,8-s), no diag) -> partial 0
//   slot s>=8: TAIL of q-tile qB=s (kb in [s-7,s], diag at end)  -> partial 1
// Every block runs 8-9 units (vs 1..16 before): critical path ~0.56x at identical
// occupancy (4 blocks/CU). Partials (raw o f32 + l) -> po/pl; combine kernel finishes.
constexpr int KSZ = 64*64;

__global__ __launch_bounds__(256,4) void attn_kernel(
    const bf16* __restrict__ Q, const bf16* __restrict__ Km,
    const bf16* __restrict__ Vt, bf16* __restrict__ O,
    float* __restrict__ po, float* __restrict__ pl)
{
  __shared__ __align__(16) char smem[32768];
  bf16* Ks = (bf16*)smem;              // [2][4096]
  bf16* Vs = (bf16*)(smem + 16384);    // [2][4096]

  const int s  = blockIdx.y;          // 0..15
  const int bh = blockIdx.x;          // 0..63 -> XCD = bh%8
  const int b = bh >> 4, h = bh & 15;
  const int tid = threadIdx.x;
  const int w = tid>>6, lane = tid&63, quad = lane>>4, l16 = lane&15;
  const size_t qbase = (size_t)b*1024*1024 + (size_t)h*64;
  const size_t vbase = (size_t)(bh*64)*1024;

  const bool two = (s < 8);
  const int qA = s;
  const int qB = two ? (15 - s) : s;
  const int aN = two ? (s + 1) : 0;
  const int bLo = two ? 0 : (s - 7);
  const int total = aN + (two ? (8 - s) : 8);   // 9 (s<8) or 8

  const int rowA = qA*64 + w*16 + l16;
  const int rowB = qB*64 + w*16 + l16;

  // Q as B-frag (prescaled by log2e/32): load both tiles' fragments
  const bf16* qpA = Q + qbase + (size_t)rowA*1024 + quad*8;
  const bf16* qpB = Q + qbase + (size_t)rowB*1024 + quad*8;
  bf16x8 bqA0 = *(const bf16x8*)qpA, bqA1 = *(const bf16x8*)(qpA + 32);
  bf16x8 bqB0 = *(const bf16x8*)qpB, bqB1 = *(const bf16x8*)(qpB + 32);

  f32x4 oA[4] = {}, oB[4] = {};
  float lA = 0.f, lB = 0.f;
  const f32x4 zf = {0.f,0.f,0.f,0.f};

  const bf16* kg = Km + qbase + (size_t)(w*8 + (lane>>3))*1024 + ((lane&7)^(lane>>3))*8;
  const bf16* vg = Vt + vbase + (size_t)(w*8 + (lane>>3))*1024 + ((lane&7)^(lane>>3))*8;

  // prologue: stage unit 0
  {
    const int kb0 = two ? 0 : bLo;
    GLL16(kg + (size_t)kb0*64*1024,                   Ks + w*512);
    GLL16(kg + (size_t)kb0*64*1024 + (size_t)32*1024, Ks + 2048 + w*512);
    GLL16(vg + kb0*64,                                Vs + w*512);
    GLL16(vg + kb0*64 + (size_t)32*1024,              Vs + 2048 + w*512);
  }

  for(int u = 0; u < total; u++){
    const int cur = u & 1;
    __syncthreads();

    if(u + 1 < total){
      const int kbn = (u+1 < aN) ? (u+1) : (bLo + (u+1) - aN);
      const bf16* kgp = kg + (size_t)kbn*64*1024;
      const bf16* vgp = vg + kbn*64;
      bf16* kd = Ks + (cur^1)*KSZ + w*512;
      bf16* vd = Vs + (cur^1)*KSZ + w*512;
      GLL16(kgp,                   kd);
      GLL16(kgp + (size_t)32*1024, kd + 2048);
      GLL16(vgp,                   vd);
      GLL16(vgp + (size_t)32*1024, vd + 2048);
    }

    const bool inA = (u < aN);
    const int kb = inA ? u : (bLo + u - aN);
    const bool diag = inA ? (kb == qA) : (!two && (u == total-1));
    const int nc = diag ? (w+1) : 4;
    const int myrow = inA ? rowA : rowB;
    const bf16* ksb = Ks + cur*KSZ;
    const bf16* vsb = Vs + cur*KSZ;

    f32x4 sx[4];
#pragma unroll
    for(int c=0;c<4;c++){
      if(c >= nc) continue;
      const int row = c*16 + l16;
      const bf16* rp = ksb + row*64;
      bf16x8 ak0 = *(const bf16x8*)(rp + (( quad      ^ (row&7))<<3));
      bf16x8 ak1 = *(const bf16x8*)(rp + (((quad^4)   ^ (row&7))<<3));
      if(inA){
        sx[c] = MFMA32(ak0, bqA0, zf);
        sx[c] = MFMA32(ak1, bqA1, sx[c]);
      } else {
        sx[c] = MFMA32(ak0, bqB0, zf);
        sx[c] = MFMA32(ak1, bqB1, sx[c]);
      }
    }

    s16x4 pp[4];
    float lacc = 0.f;
#pragma unroll
    for(int c=0;c<4;c++){
      if(c >= nc) continue;
      bf16x4 pb;
#pragma unroll
      for(int g=0;g<4;g++){
        const int key = kb*64 + c*16 + quad*4 + g;
        const float e = (diag && key > myrow) ? 0.f : EXP2F(sx[c][g]);
        lacc += e; pb[g] = (bf16)e;
      }
      pp[c] = __builtin_bit_cast(s16x4, pb);
    }
    if(inA) lA += lacc; else lB += lacc;

#pragma unroll
    for(int c=0;c<4;c++){
      if(c >= nc) continue;
#pragma unroll
      for(int d=0;d<4;d++){
        const int row = d*16 + l16;
        const int eo  = ((((c*2 + (quad>>1)) ^ (row&7))<<3) + ((quad&1)<<2));
        bf16x4 av = *(const bf16x4*)(vsb + row*64 + eo);
        if(inA) oA[d] = MFMA16(__builtin_bit_cast(s16x4, av), pp[c], oA[d]);
        else    oB[d] = MFMA16(__builtin_bit_cast(s16x4, av), pp[c], oB[d]);
      }
    }
  }

  lA += __shfl_xor(lA, 16); lA += __shfl_xor(lA, 32);
  lB += __shfl_xor(lB, 16); lB += __shfl_xor(lB, 32);

  __syncthreads();                     // staging reads done; smem reusable

  if(two){
    // full O for qA: wave-private bf16 bounce at smem[0..9216)
    bf16* ot = (bf16*)smem + w*(16*72);
    const float inv = 1.0f / lA;
#pragma unroll
    for(int d=0;d<4;d++)
#pragma unroll
      for(int g=0;g<4;g++)
        ot[l16*72 + d*16 + quad*4 + g] = (bf16)(oA[d][g]*inv);
#pragma unroll
    for(int p2=0;p2<2;p2++){
      const int qr = (lane>>3) + 8*p2, hd0 = (lane&7)*8;
      bf16x8 val = *(const bf16x8*)(ot + qr*72 + hd0);
      *(bf16x8*)(O + qbase + (size_t)(qA*64 + w*16 + qr)*1024 + hd0) = val;
    }
  }

  // B partial (all slots): raw oB / lB
  const int pslot = ((bh*8 + (qB-8))<<1) + (two ? 0 : 1);
  if(quad == 0) pl[pslot*64 + w*16 + l16] = lB;
  float* ot32 = (float*)(smem + 9216);   // [64][65] f32, disjoint from bf16 bounce
#pragma unroll
  for(int d=0;d<4;d++)
#pragma unroll
    for(int g=0;g<4;g++)
      ot32[(w*16 + l16)*65 + d*16 + quad*4 + g] = oB[d][g];
  __syncthreads();
  {
    const int r = tid>>2, c16 = (tid&3)*16;
    float* dst = po + (size_t)pslot*4096 + r*64 + c16;
#pragma unroll
    for(int j=0;j<4;j++){
      float4 v;
      v.x = ot32[r*65 + c16 + 4*j];
      v.y = ot32[r*65 + c16 + 4*j + 1];
      v.z = ot32[r*65 + c16 + 4*j + 2];
      v.w = ot32[r*65 + c16 + 4*j + 3];
      *(float4*)(dst + 4*j) = v;
    }
  }
}

// combine the two partials of each high q-tile (qt>=8), normalize, write O
__global__ __launch_bounds__(256) void attn_combine_kernel(
    const float* __restrict__ po, const float* __restrict__ pl, bf16* __restrict__ O)
{
  const int bh = blockIdx.x, qth = blockIdx.y;
  const int b = bh >> 4, h = bh & 15;
  const int qt = 8 + qth;
  const int t = threadIdx.x;
  const int r = t >> 2, c16 = (t & 3) * 16;
  const size_t base0 = ((size_t)(bh*8 + qth)*2)*4096 + r*64 + c16;
  const size_t base1 = base0 + 4096;
  const float lsum = pl[(bh*8+qth)*128 + r] + pl[(bh*8+qth)*128 + 64 + r];
  const float inv = 1.0f / lsum;
  __align__(16) bf16 outv[16];
#pragma unroll
  for(int j=0;j<4;j++){
    float4 a = *(const float4*)(po + base0 + 4*j);
    float4 c = *(const float4*)(po + base1 + 4*j);
    outv[4*j  ] = (bf16)((a.x + c.x)*inv);
    outv[4*j+1] = (bf16)((a.y + c.y)*inv);
    outv[4*j+2] = (bf16)((a.z + c.z)*inv);
    outv[4*j+3] = (bf16)((a.w + c.w)*inv);
  }
  bf16* op = O + (size_t)b*1024*1024 + (size_t)(qt*64 + r)*1024 + h*64 + c16;
  *(bf16x8*)op     = *(bf16x8*)outv;
  *(bf16x8*)(op+8) = *(bf16x8*)(outv+8);
}

// ---------------- launch ----------------
extern "C" void kernel_launch(void* const* d_in, const int* in_sizes, int n_in,
                              void* d_out, int out_size, void* d_ws, size_t ws_size,
                              hipStream_t stream)
{
  const float* x_in = (const float*)d_in[0];
  const float* emb  = (const float*)d_in[1];
  const float* Wq   = (const float*)d_in[2];
  const float* Wk   = (const float*)d_in[3];
  const float* Wv   = (const float*)d_in[4];
  const float* fcw  = (const float*)d_in[5];
  const float* fcb  = (const float*)d_in[6];
  const float* ln1w = (const float*)d_in[7];
  const float* ln1b = (const float*)d_in[8];
  const float* ln2w = (const float*)d_in[9];
  const float* ln2b = (const float*)d_in[10];
  const float* w1   = (const float*)d_in[11];
  const float* b1   = (const float*)d_in[12];
  const float* w2   = (const float*)d_in[13];
  const float* b2   = (const float*)d_in[14];
  const float* w3   = (const float*)d_in[15];
  const float* b3   = (const float*)d_in[16];

  char* ws = (char*)d_ws;
  const size_t MB = 1024*1024;
  float* cur    = (float*)(ws + 0);
  float* x1     = (float*)(ws + 16*MB);
  float* po     = (float*)(ws + 32*MB);   // 64bh x 8qt x 2parts x 4096 f32 = 16MB
  bf16*  hb     = (bf16*)(ws + 48*MB);
  bf16*  attnb  = (bf16*)(ws + 56*MB);
  bf16*  qb     = (bf16*)(ws + 64*MB);
  bf16*  kbuf   = (bf16*)(ws + 72*MB);
  bf16*  vtb    = (bf16*)(ws + 80*MB);    // V^T per-head: [(b*16+h)*64+hd][t]
  bf16*  w1pl   = (bf16*)(ws + 88*MB);
  bf16*  T12    = (bf16*)(ws + 92*MB);
  bf16*  wqkvT  = (bf16*)(ws + 96*MB);
  bf16*  fcT    = (bf16*)(ws + 102*MB);
  bf16*  w2T    = (bf16*)(ws + 104*MB);
  bf16*  w3T    = (bf16*)(ws + 108*MB);
  bf16*  WeffT  = (bf16*)(ws + 110*MB);
  float* tmpb   = (float*)(ws + 112*MB);
  float* beff   = (float*)(ws + 112*MB + 8192);
  float* pl     = (float*)(ws + 114*MB);  // 64bh x 8qt x 2parts x 64 f32 = 256KB

  pack_all_kernel<<<2816,256,0,stream>>>(Wq, Wk, Wv, fcw, w2, w3, w1,
                                         wqkvT, fcT, w2T, w3T, w1pl);
  gemm_kernel<0,64,2><<<dim3(8,16),256,0,stream>>>(w1pl, w2T, nullptr, T12,   nullptr, nullptr, nullptr, nullptr, nullptr, nullptr, 1024, 2048);
  gemm_kernel<0,64,2><<<dim3(8,16),256,0,stream>>>(w3T,  T12, nullptr, WeffT, nullptr, nullptr, nullptr, nullptr, nullptr, nullptr, 1024, 1024);
  biasmv_kernel<<<1024,256,0,stream>>>(b1,   w2T, b2, tmpb, 2048);
  biasmv_kernel<<<1024,256,0,stream>>>(tmpb, w3T, b3, beff, 1024);

  // t=0: cur = x_in + x_in + emb[0]; hb = LN1(cur)
  add_ln_kernel<<<4096,256,0,stream>>>(x_in, x_in, emb, ln1w, ln1b, cur, hb);
  for(int t=0; t<8; t++){
    if(t > 0)
      add_ln_kernel<<<4096,256,0,stream>>>(cur, nullptr, nullptr, ln1w, ln1b, nullptr, hb);
    gemm_kernel<4,128,1><<<dim3(24,32),256,0,stream>>>(hb, wqkvT, nullptr, qb, kbuf, vtb, nullptr, nullptr, nullptr, nullptr, 3072, 1024);
    attn_kernel<<<dim3(64,16),256,0,stream>>>(qb, kbuf, vtb, attnb, po, pl);
    attn_combine_kernel<<<dim3(64,8),256,0,stream>>>(po, pl, attnb);
    gemm_kernel<2,64,2><<<dim3(8,64),256,0,stream>>>(attnb, fcT, x1, nullptr, nullptr, nullptr, fcb, cur, nullptr, nullptr, 1024, 1024);
    add_ln_kernel<<<4096,256,0,stream>>>(x1, nullptr, nullptr, ln2w, ln2b, nullptr, hb);
    if(t < 7)
      gemm_kernel<5,64,2><<<dim3(8,64),256,0,stream>>>(hb, WeffT, cur, nullptr, nullptr, nullptr, beff, x1, cur, emb + (t+1)*1024, 1024, 1024);
    else
      gemm_kernel<3,64,2><<<dim3(8,64),256,0,stream>>>(hb, WeffT, (float*)d_out, nullptr, nullptr, nullptr, beff, x1, nullptr, nullptr, 1024, 1024);
  }
}

// Round 11
// 987.673 us; speedup vs baseline: 1.1108x; 1.1108x over previous
//
#include <hip/hip_runtime.h>
#include <hip/hip_bf16.h>
#include <math.h>

typedef __bf16 bf16;
typedef __bf16 bf16x8 __attribute__((ext_vector_type(8)));
typedef __bf16 bf16x4 __attribute__((ext_vector_type(4)));
typedef short  s16x4  __attribute__((ext_vector_type(4)));
typedef float  f32x4  __attribute__((ext_vector_type(4)));

#define MFMA32(a,b,c) __builtin_amdgcn_mfma_f32_16x16x32_bf16((a),(b),(c),0,0,0)
#define MFMA16(a,b,c) __builtin_amdgcn_mfma_f32_16x16x16bf16_1k((a),(b),(c),0,0,0)
#define EXP2F(x) __builtin_amdgcn_exp2f(x)
// async global->LDS, 16B per lane; LDS dest is wave-uniform base + lane*16 (m104/m108)
#define GLL16(gp, lp) __builtin_amdgcn_global_load_lds(\
    (const __attribute__((address_space(1))) void*)(gp), \
    (__attribute__((address_space(3))) void*)(lp), 16, 0, 0)

__device__ __forceinline__ float wave_sum(float v){
#pragma unroll
  for(int off=1; off<64; off<<=1) v += __shfl_xor(v, off);
  return v;
}

// ---------------- fused (add) + layernorm -> bf16 (round-1 verbatim) ----------------
__global__ __launch_bounds__(256) void add_ln_kernel(
    const float* __restrict__ xsrc, const float* __restrict__ addsrc,
    const float* __restrict__ emb,
    const float* __restrict__ gw, const float* __restrict__ gb,
    float* __restrict__ xout, bf16* __restrict__ hout)
{
  const int row = blockIdx.x;
  const int t = threadIdx.x;
  const size_t rbase = (size_t)row * 1024;
  float4 x = ((const float4*)(xsrc + rbase))[t];
  if(addsrc){
    float4 a = ((const float4*)(addsrc + rbase))[t];
    x.x += a.x; x.y += a.y; x.z += a.z; x.w += a.w;
  }
  if(emb){
    float4 e = ((const float4*)emb)[t];
    x.x += e.x; x.y += e.y; x.z += e.z; x.w += e.w;
  }
  if(xout) ((float4*)(xout + rbase))[t] = x;

  float s = x.x + x.y + x.z + x.w;
  float q = x.x*x.x + x.y*x.y + x.z*x.z + x.w*x.w;
  s = wave_sum(s); q = wave_sum(q);
  __shared__ float red[8];
  const int w = t >> 6;
  if((t & 63) == 0){ red[w] = s; red[4+w] = q; }
  __syncthreads();
  s = red[0]+red[1]+red[2]+red[3];
  q = red[4]+red[5]+red[6]+red[7];
  const float mean = s * (1.0f/1024.0f);
  const float var  = q * (1.0f/1024.0f) - mean*mean;
  const float inv  = rsqrtf(var + 1e-5f);

  float4 wv = ((const float4*)gw)[t];
  float4 bv = ((const float4*)gb)[t];
  bf16x4 hv;
  hv[0] = (bf16)((x.x - mean)*inv*wv.x + bv.x);
  hv[1] = (bf16)((x.y - mean)*inv*wv.y + bv.y);
  hv[2] = (bf16)((x.z - mean)*inv*wv.z + bv.z);
  hv[3] = (bf16)((x.w - mean)*inv*wv.w + bv.w);
  *(bf16x4*)(hout + rbase + t*4) = hv;
}

// ---------------- merged weight packing, LDS-tiled transposes (round-9 verbatim) ----------------
__global__ __launch_bounds__(256) void pack_all_kernel(
    const float* __restrict__ Wq, const float* __restrict__ Wk, const float* __restrict__ Wv,
    const float* __restrict__ fcw, const float* __restrict__ w2,
    const float* __restrict__ w3,  const float* __restrict__ w1,
    bf16* __restrict__ wqkvT, bf16* __restrict__ fcT,
    bf16* __restrict__ w2T,   bf16* __restrict__ w3T, bf16* __restrict__ w1pl)
{
  const int bid = blockIdx.x;
  const int tid = threadIdx.x;
  if(bid >= 1792){                       // w1 cast: 2M elems, flat coalesced
    const int i0 = (bid-1792)*2048 + tid*8;
    float4 a = *(const float4*)(w1 + i0);
    float4 b = *(const float4*)(w1 + i0 + 4);
    bf16x8 o;
    o[0]=(bf16)a.x; o[1]=(bf16)a.y; o[2]=(bf16)a.z; o[3]=(bf16)a.w;
    o[4]=(bf16)b.x; o[5]=(bf16)b.y; o[6]=(bf16)b.z; o[7]=(bf16)b.w;
    *(bf16x8*)(w1pl + i0) = o;
    return;
  }

  __shared__ float tile[64][65];
  const float* src; bf16* dst;
  int src_ld, dst_ld;
  if(bid < 768){                         // qkv
    const int seg = bid >> 8, r8 = bid & 255;
    const int h = r8 >> 4, d0 = (r8 & 15)*64;
    const float* W = (seg==0) ? Wq : (seg==1 ? Wk : Wv);
    src = W + h*65536 + (size_t)d0*64;  src_ld = 64;
    dst = wqkvT + ((size_t)(seg*1024 + h*64))*1024 + d0;  dst_ld = 1024;
  } else if(bid < 1024){                 // fcT
    const int t2 = bid - 768;
    const int k0 = (t2 >> 4)*64, n0 = (t2 & 15)*64;
    src = fcw + (size_t)k0*1024 + n0;  src_ld = 1024;
    dst = fcT + (size_t)n0*1024 + k0;  dst_ld = 1024;
  } else if(bid < 1536){                 // w2T
    const int t2 = bid - 1024;
    const int k0 = (t2 >> 4)*64, n0 = (t2 & 15)*64;
    src = w2 + (size_t)k0*1024 + n0;  src_ld = 1024;
    dst = w2T + (size_t)n0*2048 + k0;  dst_ld = 2048;
  } else {                               // w3T
    const int t2 = bid - 1536;
    const int k0 = (t2 >> 4)*64, n0 = (t2 & 15)*64;
    src = w3 + (size_t)k0*1024 + n0;  src_ld = 1024;
    dst = w3T + (size_t)n0*1024 + k0;  dst_ld = 1024;
  }

  {
    const int r = tid >> 4, c4 = (tid & 15)*4;
#pragma unroll
    for(int p=0; p<4; p++){
      float4 v = *(const float4*)(src + (size_t)(r + 16*p)*src_ld + c4);
      tile[r+16*p][c4]   = v.x;
      tile[r+16*p][c4+1] = v.y;
      tile[r+16*p][c4+2] = v.z;
      tile[r+16*p][c4+3] = v.w;
    }
  }
  __syncthreads();
  {
    const int n = tid >> 2, k16 = (tid & 3)*16;
#pragma unroll
    for(int half=0; half<2; half++){
      bf16x8 o;
#pragma unroll
      for(int j=0; j<8; j++) o[j] = (bf16)tile[k16 + half*8 + j][n];
      *(bf16x8*)(dst + (size_t)n*dst_ld + k16 + half*8) = o;
    }
  }
}

__global__ __launch_bounds__(256) void biasmv_kernel(const float* __restrict__ bin, const bf16* __restrict__ WT,
                                                     const float* __restrict__ badd, float* __restrict__ out, int Kd){
  const int n = blockIdx.x, t = threadIdx.x;
  float acc = 0.f;
  for(int k=t; k<Kd; k+=256) acc += bin[k]*(float)WT[(size_t)n*Kd + k];
  acc = wave_sum(acc);
  __shared__ float red[4];
  if((t&63)==0) red[t>>6] = acc;
  __syncthreads();
  if(t==0) out[n] = red[0]+red[1]+red[2]+red[3] + badd[n];
}

// ---------------- bf16 MFMA GEMM, BK = 64*KH (round-8/9 verbatim) ----------------
template<int EPI, int BLKM, int KH>
__global__ __launch_bounds__(256,2) void gemm_kernel(
    const bf16* __restrict__ A, const bf16* __restrict__ Bt,
    float* __restrict__ outf, bf16* __restrict__ outb,
    bf16* __restrict__ o2, bf16* __restrict__ o3,
    const float* __restrict__ bias, const float* __restrict__ res,
    const float* __restrict__ res2, const float* __restrict__ embn,
    int N, int K)
{
  constexpr int RM = BLKM/32;
  constexpr int HM = BLKM/2;
  constexpr int AISS = BLKM/32;
  __shared__ __align__(16) bf16 As[KH*BLKM*64];
  __shared__ __align__(16) bf16 Bs[KH*128*64];
  const int tid = threadIdx.x, w = tid>>6, lane = tid&63;
  const int quad = lane>>4, l16 = lane&15;
  const int wm = w&1, wn = w>>1;
  const int tn = blockIdx.x, tm = blockIdx.y;

  const int srow = lane>>3;
  const int sch  = (lane&7) ^ srow;
  const bf16* Ag = A  + (size_t)(tm*BLKM + w*8 + srow)*K + sch*8;
  const bf16* Bg = Bt + (size_t)(tn*128  + w*8 + srow)*K + sch*8;

  f32x4 acc[RM][4] = {};

  for(int k0 = 0; k0 < K; k0 += 64*KH){
#pragma unroll
    for(int h=0; h<KH; h++){
#pragma unroll
      for(int i=0;i<AISS;i++) GLL16(Ag + h*64 + (size_t)(i*32)*K, As + h*(BLKM*64) + (w*8 + i*32)*64);
#pragma unroll
      for(int i=0;i<4;i++)    GLL16(Bg + h*64 + (size_t)(i*32)*K, Bs + h*(128*64) + (w*8 + i*32)*64);
    }
    Ag += 64*KH; Bg += 64*KH;
    __syncthreads();
#pragma unroll
    for(int h=0; h<KH; h++){
      const bf16* Ash = As + h*(BLKM*64);
      const bf16* Bsh = Bs + h*(128*64);
      bf16x8 af[RM][2], bfr[4][2];
#pragma unroll
      for(int r=0;r<RM;r++){
        const int row = wm*HM + r*16 + l16;
        const bf16* rp = Ash + row*64;
#pragma unroll
        for(int kc=0;kc<2;kc++)
          af[r][kc] = *(const bf16x8*)(rp + ((kc*4+quad) ^ (row&7))*8);
      }
#pragma unroll
      for(int c=0;c<4;c++){
        const int row = wn*64 + c*16 + l16;
        const bf16* rp = Bsh + row*64;
#pragma unroll
        for(int kc=0;kc<2;kc++)
          bfr[c][kc] = *(const bf16x8*)(rp + ((kc*4+quad) ^ (row&7))*8);
      }
#pragma unroll
      for(int kc=0;kc<2;kc++)
#pragma unroll
        for(int r=0;r<RM;r++)
#pragma unroll
          for(int c=0;c<4;c++)
            acc[r][c] = MFMA32(af[r][kc], bfr[c][kc], acc[r][c]);
    }
    __syncthreads();
  }

  // C/D: col = lane&15, row = quad*4 + reg
#pragma unroll
  for(int r=0;r<RM;r++){
    const int grow0 = tm*BLKM + wm*HM + r*16 + quad*4;
#pragma unroll
    for(int c=0;c<4;c++){
      const int gcol = tn*128 + wn*64 + c*16 + l16;
      float bv = 0.0f;
      if constexpr (EPI>=1 && EPI!=4) bv = bias[gcol];
      if constexpr (EPI==4){
        const int seg = gcol >> 10;          // wave-uniform
        if(seg < 2){
          bf16* op = (seg==0) ? outb : o2;
          // q: fold 1024^-0.5 * log2(e) so attention uses raw v_exp_f32 (exp2)
          const float qs = (seg==0) ? 0.045084439f : 1.0f;
          const int col = gcol & 1023;
#pragma unroll
          for(int g=0; g<4; g++)
            op[(size_t)(grow0+g)*1024 + col] = (bf16)(acc[r][c][g]*qs);
        } else {
          const int col0 = gcol & 1023, hh = col0>>6, kk = col0&63;
          const int btok = grow0>>10, t0 = grow0&1023;
          bf16x4 pv;
#pragma unroll
          for(int g=0; g<4; g++) pv[g] = (bf16)acc[r][c][g];
          *(bf16x4*)(o3 + ((size_t)(btok*16+hh)*64 + kk)*1024 + t0) = pv;
        }
      } else {
        const float ev = (EPI==5) ? embn[gcol] : 0.0f;
#pragma unroll
        for(int g=0; g<4; g++){
          const float vv = acc[r][c][g] + bv;
          const size_t idx = (size_t)(grow0+g)*N + gcol;
          if constexpr (EPI<=1){
            outb[idx] = (bf16)vv;
          } else if constexpr (EPI==2){
            outf[idx] = res[idx] + vv;
          } else if constexpr (EPI==3){
            const float gel = 0.5f*vv*(1.0f + erff(vv*0.70710678118654752f));
            outf[idx] = res[idx] + gel;
          } else {
            const float gel = 0.5f*vv*(1.0f + erff(vv*0.70710678118654752f));
            outf[idx] = res[idx] + gel + res2[idx] + ev;
          }
        }
      }
    }
  }
}

// ---------------- fused causal attention (round-9 structure + balanced qt permutation) ----------------
// grid (64 bh, 16 sy): 1024 blocks co-resident, 4 blocks/CU. Under both plausible dispatch
// models (CU round-robin by block id, or XCD-first), CU c receives slots {g, g+4, g+8, g+12},
// g in [0,4). With qt = sy (identity), per-CU work = 4g+28 in [28,40] units (1.18x imbalance).
// perm = {0,1,2,3, 5,4,7,6, 10,11,8,9, 15,14,13,12} makes every such group sum to 30+4diag:
// per-CU work equalized at 34 units. Any bijection is CORRECT; balance is only a heuristic.
// K/V staged via global_load_lds (async, linear LDS dest), XOR-pre-swizzled source, dbuf.
// No online max: Q prescaled by log2e/32 -> raw v_exp_f32; masked keys -> 0.
constexpr int KSZ = 64*64;

__global__ __launch_bounds__(256,4) void attn_kernel(
    const bf16* __restrict__ Q, const bf16* __restrict__ Km,
    const bf16* __restrict__ Vt, bf16* __restrict__ O)
{
  __shared__ __align__(16) bf16 Ks[2*KSZ];   // [buf][key][hd]   (chunk-swizzled)
  __shared__ __align__(16) bf16 Vs[2*KSZ];   // [buf][hd][key]   (chunk-swizzled)
  const int qt = (int)((0xCDEF98BA67453210ull >> (blockIdx.y*4)) & 15);  // balanced slot->tile
  const int bh = blockIdx.x;          // 0..63 -> XCD = bh%8
  const int b = bh >> 4, h = bh & 15;
  const int tid = threadIdx.x;
  const int w = tid>>6, lane = tid&63, quad = lane>>4, l16 = lane&15;
  const size_t qbase = (size_t)b*1024*1024 + (size_t)h*64;
  const size_t vbase = (size_t)(bh*64)*1024;
  const int qrow0 = qt*64 + w*16;
  const int myrow = qrow0 + l16;

  const bf16* qp = Q + qbase + (size_t)myrow*1024 + quad*8;
  bf16x8 bq0 = *(const bf16x8*)qp, bq1 = *(const bf16x8*)(qp + 32);

  f32x4 o[4] = {};
  float l = 0.f;
  const f32x4 zf = {0.f,0.f,0.f,0.f};

  const bf16* kg = Km + qbase + (size_t)(w*8 + (lane>>3))*1024 + ((lane&7)^(lane>>3))*8;
  const bf16* vg = Vt + vbase + (size_t)(w*8 + (lane>>3))*1024 + ((lane&7)^(lane>>3))*8;

  // prologue: stage kb=0 into buffer 0 (async; drained by first __syncthreads)
  GLL16(kg,                       Ks + w*512);
  GLL16(kg + (size_t)32*1024,     Ks + 2048 + w*512);
  GLL16(vg,                       Vs + w*512);
  GLL16(vg + (size_t)32*1024,     Vs + 2048 + w*512);

  for(int kb = 0; kb <= qt; kb++){
    const int cur = kb & 1;
    __syncthreads();

    if(kb < qt){
      const bf16* kgp = kg + (size_t)(kb+1)*64*1024;
      const bf16* vgp = vg + (size_t)(kb+1)*64;
      bf16* kd = Ks + (cur^1)*KSZ + w*512;
      bf16* vd = Vs + (cur^1)*KSZ + w*512;
      GLL16(kgp,                   kd);
      GLL16(kgp + (size_t)32*1024, kd + 2048);
      GLL16(vgp,                   vd);
      GLL16(vgp + (size_t)32*1024, vd + 2048);
    }

    const bool diag = (kb == qt);
    const int nc = diag ? (w+1) : 4;
    const bf16* ksb = Ks + cur*KSZ;
    const bf16* vsb = Vs + cur*KSZ;

    f32x4 s[4];
#pragma unroll
    for(int c=0;c<4;c++){
      if(c >= nc) continue;
      const int row = c*16 + l16;
      const bf16* rp = ksb + row*64;
      bf16x8 ak0 = *(const bf16x8*)(rp + (( quad      ^ (row&7))<<3));
      bf16x8 ak1 = *(const bf16x8*)(rp + (((quad^4)   ^ (row&7))<<3));
      s[c] = MFMA32(ak0, bq0, zf);
      s[c] = MFMA32(ak1, bq1, s[c]);
    }

    s16x4 pp[4];
#pragma unroll
    for(int c=0;c<4;c++){
      if(c >= nc) continue;
      bf16x4 pb;
#pragma unroll
      for(int g=0;g<4;g++){
        const int key = kb*64 + c*16 + quad*4 + g;
        const float e = (diag && key > myrow) ? 0.f : EXP2F(s[c][g]);
        l += e; pb[g] = (bf16)e;
      }
      pp[c] = __builtin_bit_cast(s16x4, pb);
    }

#pragma unroll
    for(int c=0;c<4;c++){
      if(c >= nc) continue;
#pragma unroll
      for(int d=0;d<4;d++){
        const int row = d*16 + l16;
        const int eo  = ((((c*2 + (quad>>1)) ^ (row&7))<<3) + ((quad&1)<<2));
        bf16x4 av = *(const bf16x4*)(vsb + row*64 + eo);
        o[d] = MFMA16(__builtin_bit_cast(s16x4, av), pp[c], o[d]);
      }
    }
  }

  l += __shfl_xor(l, 16); l += __shfl_xor(l, 32);

  __syncthreads();
  {
    bf16* ot = Ks + w*(16*72);
    const float inv = 1.0f / l;
#pragma unroll
    for(int d=0;d<4;d++)
#pragma unroll
      for(int g=0;g<4;g++)
        ot[l16*72 + d*16 + quad*4 + g] = (bf16)(o[d][g]*inv);
#pragma unroll
    for(int p2=0;p2<2;p2++){
      const int qr = (lane>>3) + 8*p2, hd0 = (lane&7)*8;
      bf16x8 val = *(const bf16x8*)(ot + qr*72 + hd0);
      *(bf16x8*)(O + qbase + (size_t)(qrow0+qr)*1024 + hd0) = val;
    }
  }
}

// ---------------- launch ----------------
extern "C" void kernel_launch(void* const* d_in, const int* in_sizes, int n_in,
                              void* d_out, int out_size, void* d_ws, size_t ws_size,
                              hipStream_t stream)
{
  const float* x_in = (const float*)d_in[0];
  const float* emb  = (const float*)d_in[1];
  const float* Wq   = (const float*)d_in[2];
  const float* Wk   = (const float*)d_in[3];
  const float* Wv   = (const float*)d_in[4];
  const float* fcw  = (const float*)d_in[5];
  const float* fcb  = (const float*)d_in[6];
  const float* ln1w = (const float*)d_in[7];
  const float* ln1b = (const float*)d_in[8];
  const float* ln2w = (const float*)d_in[9];
  const float* ln2b = (const float*)d_in[10];
  const float* w1   = (const float*)d_in[11];
  const float* b1   = (const float*)d_in[12];
  const float* w2   = (const float*)d_in[13];
  const float* b2   = (const float*)d_in[14];
  const float* w3   = (const float*)d_in[15];
  const float* b3   = (const float*)d_in[16];

  char* ws = (char*)d_ws;
  const size_t MB = 1024*1024;
  float* cur    = (float*)(ws + 0);
  float* x1     = (float*)(ws + 16*MB);
  bf16*  hb     = (bf16*)(ws + 48*MB);
  bf16*  attnb  = (bf16*)(ws + 56*MB);
  bf16*  qb     = (bf16*)(ws + 64*MB);
  bf16*  kbuf   = (bf16*)(ws + 72*MB);
  bf16*  vtb    = (bf16*)(ws + 80*MB);    // V^T per-head: [(b*16+h)*64+hd][t]
  bf16*  w1pl   = (bf16*)(ws + 88*MB);
  bf16*  T12    = (bf16*)(ws + 92*MB);
  bf16*  wqkvT  = (bf16*)(ws + 96*MB);
  bf16*  fcT    = (bf16*)(ws + 102*MB);
  bf16*  w2T    = (bf16*)(ws + 104*MB);
  bf16*  w3T    = (bf16*)(ws + 108*MB);
  bf16*  WeffT  = (bf16*)(ws + 110*MB);
  float* tmpb   = (float*)(ws + 112*MB);
  float* beff   = (float*)(ws + 112*MB + 8192);

  pack_all_kernel<<<2816,256,0,stream>>>(Wq, Wk, Wv, fcw, w2, w3, w1,
                                         wqkvT, fcT, w2T, w3T, w1pl);
  gemm_kernel<0,64,2><<<dim3(8,16),256,0,stream>>>(w1pl, w2T, nullptr, T12,   nullptr, nullptr, nullptr, nullptr, nullptr, nullptr, 1024, 2048);
  gemm_kernel<0,64,2><<<dim3(8,16),256,0,stream>>>(w3T,  T12, nullptr, WeffT, nullptr, nullptr, nullptr, nullptr, nullptr, nullptr, 1024, 1024);
  biasmv_kernel<<<1024,256,0,stream>>>(b1,   w2T, b2, tmpb, 2048);
  biasmv_kernel<<<1024,256,0,stream>>>(tmpb, w3T, b3, beff, 1024);

  // t=0: cur = x_in + x_in + emb[0]; hb = LN1(cur)
  add_ln_kernel<<<4096,256,0,stream>>>(x_in, x_in, emb, ln1w, ln1b, cur, hb);
  for(int t=0; t<8; t++){
    if(t > 0)
      add_ln_kernel<<<4096,256,0,stream>>>(cur, nullptr, nullptr, ln1w, ln1b, nullptr, hb);
    gemm_kernel<4,128,1><<<dim3(24,32),256,0,stream>>>(hb, wqkvT, nullptr, qb, kbuf, vtb, nullptr, nullptr, nullptr, nullptr, 3072, 1024);
    attn_kernel<<<dim3(64,16),256,0,stream>>>(qb, kbuf, vtb, attnb);
    gemm_kernel<2,64,2><<<dim3(8,64),256,0,stream>>>(attnb, fcT, x1, nullptr, nullptr, nullptr, fcb, cur, nullptr, nullptr, 1024, 1024);
    add_ln_kernel<<<4096,256,0,stream>>>(x1, nullptr, nullptr, ln2w, ln2b, nullptr, hb);
    if(t < 7)
      gemm_kernel<5,64,2><<<dim3(8,64),256,0,stream>>>(hb, WeffT, cur, nullptr, nullptr, nullptr, beff, x1, cur, emb + (t+1)*1024, 1024, 1024);
    else
      gemm_kernel<3,64,2><<<dim3(8,64),256,0,stream>>>(hb, WeffT, (float*)d_out, nullptr, nullptr, nullptr, beff, x1, nullptr, nullptr, 1024, 1024);
  }
}